// Round 2
// baseline (308.701 us; speedup 1.0000x reference)
//
#include <hip/hip_runtime.h>
#include <hip/hip_bf16.h>
#include <math.h>

#define N_NODES 4096
#define D_EMB   512
#define D_GNN   256
#define D_HEAD  128
#define FUS     768
#define D_HID   384   // FUS/2
#define MAX_NBR 512

// ---------------- block reduce (256 threads, 4 waves) ----------------
__device__ __forceinline__ float block_reduce(float v, float* red, bool is_max) {
    #pragma unroll
    for (int o = 32; o; o >>= 1)
        v = is_max ? fmaxf(v, __shfl_down(v, o)) : v + __shfl_down(v, o);
    const int wid = threadIdx.x >> 6;
    if ((threadIdx.x & 63) == 0) red[wid] = v;
    __syncthreads();
    float r;
    if (is_max) r = fmaxf(fmaxf(red[0], red[1]), fmaxf(red[2], red[3]));
    else        r = red[0] + red[1] + red[2] + red[3];
    __syncthreads();   // make red reusable
    return r;
}

// ---------------- generic fp32 tiled GEMM: C = [gelu](A@B + bias) ----------------
// A: MxK row-major, B: KxN row-major, C: MxN. M%64==0, N%64==0, K%16==0.
template<bool GELU, bool HASB>
__global__ __launch_bounds__(256) void gemm64(const float* __restrict__ A,
                                              const float* __restrict__ B,
                                              const float* __restrict__ bias,
                                              float* __restrict__ C,
                                              int M, int Nn, int K) {
    __shared__ float As[16][64];
    __shared__ float Bs[16][64];
    const int t  = threadIdx.x;
    const int n0 = blockIdx.x * 64;
    const int m0 = blockIdx.y * 64;
    const int tx = t & 15, ty = t >> 4;
    const int arow = t >> 2,  ac4 = (t & 3) * 4;
    const int brow = t >> 4,  bc4 = (t & 15) * 4;
    float acc[4][4] = {};
    for (int k0 = 0; k0 < K; k0 += 16) {
        const float4 av = *(const float4*)&A[(size_t)(m0 + arow) * K + k0 + ac4];
        const float4 bv = *(const float4*)&B[(size_t)(k0 + brow) * Nn + n0 + bc4];
        __syncthreads();
        As[ac4 + 0][arow] = av.x;
        As[ac4 + 1][arow] = av.y;
        As[ac4 + 2][arow] = av.z;
        As[ac4 + 3][arow] = av.w;
        *(float4*)&Bs[brow][bc4] = bv;
        __syncthreads();
        #pragma unroll
        for (int kk = 0; kk < 16; ++kk) {
            const float4 a = *(const float4*)&As[kk][ty * 4];
            const float4 b = *(const float4*)&Bs[kk][tx * 4];
            acc[0][0] += a.x * b.x; acc[0][1] += a.x * b.y; acc[0][2] += a.x * b.z; acc[0][3] += a.x * b.w;
            acc[1][0] += a.y * b.x; acc[1][1] += a.y * b.y; acc[1][2] += a.y * b.z; acc[1][3] += a.y * b.w;
            acc[2][0] += a.z * b.x; acc[2][1] += a.z * b.y; acc[2][2] += a.z * b.z; acc[2][3] += a.z * b.w;
            acc[3][0] += a.w * b.x; acc[3][1] += a.w * b.y; acc[3][2] += a.w * b.z; acc[3][3] += a.w * b.w;
        }
    }
    float4 bcol = make_float4(0.f, 0.f, 0.f, 0.f);
    if (HASB) bcol = *(const float4*)&bias[n0 + tx * 4];
    #pragma unroll
    for (int i = 0; i < 4; ++i) {
        const int row = m0 + ty * 4 + i;
        float4 c = make_float4(acc[i][0] + bcol.x, acc[i][1] + bcol.y,
                               acc[i][2] + bcol.z, acc[i][3] + bcol.w);
        if (GELU) {
            c.x = 0.5f * c.x * (1.f + erff(c.x * 0.70710678118654752f));
            c.y = 0.5f * c.y * (1.f + erff(c.y * 0.70710678118654752f));
            c.z = 0.5f * c.z * (1.f + erff(c.z * 0.70710678118654752f));
            c.w = 0.5f * c.w * (1.f + erff(c.w * 0.70710678118654752f));
        }
        *(float4*)&C[(size_t)row * Nn + n0 + tx * 4] = c;
    }
}

// ---------------- scatter segment-sum ----------------
__global__ __launch_bounds__(256) void scatter_add(const float* __restrict__ hgnn,
                                                   const int* __restrict__ nidx,
                                                   float* __restrict__ sums,
                                                   float* __restrict__ counts) {
    const int b = blockIdx.x, t = threadIdx.x;
    const int g = nidx[b];
    atomicAdd(&sums[(size_t)g * D_GNN + t], hgnn[(size_t)b * D_GNN + t]);
    if (t == 0) atomicAdd(&counts[g], 1.0f);
}

__global__ __launch_bounds__(256) void combine(const float* __restrict__ sums,
                                               const float* __restrict__ counts,
                                               const float* __restrict__ nemb,
                                               float* __restrict__ subf) {
    const int n = blockIdx.x, t = threadIdx.x;
    const float c = counts[n];
    const size_t o = (size_t)n * D_GNN + t;
    subf[o] = (c > 0.f) ? sums[o] / fmaxf(c, 1.f) : nemb[o];
}

// ---------------- pack W_gat (H, D_GNN, d) -> B (D_GNN, H*d) ----------------
__global__ __launch_bounds__(256) void packb(const float* __restrict__ Wgat,
                                             float* __restrict__ bpack) {
    const int i = blockIdx.x, t = threadIdx.x;
    const int h = t >> 7, d = t & 127;
    bpack[(size_t)i * D_GNN + t] = Wgat[(size_t)h * D_GNN * D_HEAD + (size_t)i * D_HEAD + d];
}

// ---------------- f_src/f_dst: per-row dots with a_gat halves ----------------
__global__ __launch_bounds__(256) void fsd(const float* __restrict__ Wh,
                                           const float* __restrict__ agat,
                                           float* __restrict__ fsrc,
                                           float* __restrict__ fdst) {
    const int n = blockIdx.x * 4 + (threadIdx.x >> 6);
    const int l = threadIdx.x & 63;
    const float* row = Wh + (size_t)n * D_GNN;
    const float x0 = row[l],       x1 = row[l + 64];
    const float y0 = row[128 + l], y1 = row[192 + l];
    float s0 = x0 * agat[l]       + x1 * agat[l + 64];    // src h0
    float s1 = x0 * agat[128 + l] + x1 * agat[192 + l];   // dst h0
    float s2 = y0 * agat[256 + l] + y1 * agat[320 + l];   // src h1
    float s3 = y0 * agat[384 + l] + y1 * agat[448 + l];   // dst h1
    #pragma unroll
    for (int o = 32; o; o >>= 1) {
        s0 += __shfl_down(s0, o); s1 += __shfl_down(s1, o);
        s2 += __shfl_down(s2, o); s3 += __shfl_down(s3, o);
    }
    if (l == 0) {
        fsrc[n] = s0;            fdst[n] = s1;
        fsrc[N_NODES + n] = s2;  fdst[N_NODES + n] = s3;
    }
}

// ---------------- GAT attention + ELU + LayerNorm (one block per node) ----------------
// Deterministic neighbor compaction: per-wave ballot + cross-wave prefix keeps
// s_nbr in ascending j order (no atomic ordering jitter across runs).
__global__ __launch_bounds__(256) void gat_attn(const float* __restrict__ adj,
                                                const float* __restrict__ Wh,
                                                const float* __restrict__ fsrc,
                                                const float* __restrict__ fdst,
                                                const float* __restrict__ lng,
                                                const float* __restrict__ lnb,
                                                float* __restrict__ subout) {
    const int i = blockIdx.x, t = threadIdx.x;
    const int lane = t & 63, wid = t >> 6;
    __shared__ int   s_nbr[MAX_NBR];
    __shared__ int   s_wcnt[4];
    __shared__ int   s_base;
    __shared__ float s_att[2][MAX_NBR];
    __shared__ float s_red[4];
    __shared__ float s_inv[2];
    if (t == 0) s_base = 0;
    __syncthreads();
    const float* arow = adj + (size_t)i * N_NODES;
    // 16 chunks of 256 columns, processed in order -> ascending neighbor list
    for (int c0 = 0; c0 < N_NODES; c0 += 256) {
        const int j = c0 + t;
        const bool hit = arow[j] > 0.f;
        const unsigned long long m = __ballot(hit);
        if (lane == 0) s_wcnt[wid] = __popcll(m);
        __syncthreads();
        int wbase = s_base;
        for (int w = 0; w < wid; ++w) wbase += s_wcnt[w];
        if (hit) {
            const int p = wbase + __popcll(m & ((1ull << lane) - 1ull));
            if (p < MAX_NBR) s_nbr[p] = j;
        }
        __syncthreads();
        if (t == 0) s_base += s_wcnt[0] + s_wcnt[1] + s_wcnt[2] + s_wcnt[3];
        __syncthreads();
    }
    const int cnt = min(s_base, MAX_NBR);
    for (int h = 0; h < 2; ++h) {
        const float fs = fsrc[h * N_NODES + i];
        const float* fd = fdst + h * N_NODES;
        float lm = -1e30f;
        for (int idx = t; idx < cnt; idx += 256) {
            float e = fs + fd[s_nbr[idx]];
            e = e > 0.f ? e : 0.2f * e;     // leaky relu
            s_att[h][idx] = e;
            lm = fmaxf(lm, e);
        }
        const float m = block_reduce(lm, s_red, true);
        float ls = 0.f;
        for (int idx = t; idx < cnt; idx += 256) {
            const float p = expf(s_att[h][idx] - m);
            s_att[h][idx] = p;
            ls += p;
        }
        const float s = block_reduce(ls, s_red, false);
        if (t == 0) s_inv[h] = 1.f / s;
    }
    __syncthreads();
    const int h = t >> 7, d = t & 127;
    float acc = 0.f;
    for (int j = 0; j < cnt; ++j)
        acc += s_att[h][j] * Wh[(size_t)s_nbr[j] * D_GNN + h * D_HEAD + d];
    acc *= s_inv[h];
    const float v = acc > 0.f ? acc : expm1f(acc);   // ELU
    const float sum  = block_reduce(v, s_red, false);
    const float sq   = block_reduce(v * v, s_red, false);
    const float mean = sum * (1.f / 256.f);
    const float var  = sq * (1.f / 256.f) - mean * mean;
    const float rstd = rsqrtf(var + 1e-5f);
    subout[(size_t)i * D_GNN + t] = (v - mean) * rstd * lng[t] + lnb[t];
}

// ---------------- gather + concat + LayerNorm(768) ----------------
__global__ __launch_bounds__(256) void fuse_ln(const float* __restrict__ ht,
                                               const float* __restrict__ subout,
                                               const int* __restrict__ nidx,
                                               const float* __restrict__ g,
                                               const float* __restrict__ b,
                                               float* __restrict__ zn) {
    const int row = blockIdx.x, t = threadIdx.x;
    __shared__ float s_red[4];
    const int gidx = nidx[row];
    const float x0 = ht[(size_t)row * D_EMB + t];
    const float x1 = ht[(size_t)row * D_EMB + 256 + t];
    const float x2 = subout[(size_t)gidx * D_GNN + t];
    const float sum = block_reduce(x0 + x1 + x2, s_red, false);
    const float sq  = block_reduce(x0 * x0 + x1 * x1 + x2 * x2, s_red, false);
    const float mean = sum * (1.f / 768.f);
    const float var  = sq * (1.f / 768.f) - mean * mean;
    const float rstd = rsqrtf(var + 1e-5f);
    float* zr = zn + (size_t)row * FUS;
    zr[t]       = (x0 - mean) * rstd * g[t]       + b[t];
    zr[256 + t] = (x1 - mean) * rstd * g[256 + t] + b[256 + t];
    zr[512 + t] = (x2 - mean) * rstd * g[512 + t] + b[512 + t];
}

// ---------------- final projection: out = z1 @ W2 + b2 ----------------
__global__ __launch_bounds__(256) void outk(const float* __restrict__ z1,
                                            const float* __restrict__ W2,
                                            const float* __restrict__ b2,
                                            float* __restrict__ out) {
    const int row = blockIdx.x * 4 + (threadIdx.x >> 6);
    const int l = threadIdx.x & 63;
    float acc = 0.f;
    for (int c = l; c < D_HID; c += 64)
        acc += z1[(size_t)row * D_HID + c] * W2[c];
    #pragma unroll
    for (int o = 32; o; o >>= 1) acc += __shfl_down(acc, o);
    if (l == 0) out[row] = acc + b2[0];
}

extern "C" void kernel_launch(void* const* d_in, const int* in_sizes, int n_in,
                              void* d_out, int out_size, void* d_ws, size_t ws_size,
                              hipStream_t stream) {
    const float* ht    = (const float*)d_in[0];
    const int*   nidx  = (const int*)  d_in[1];
    const float* adj   = (const float*)d_in[2];
    const float* Wproj = (const float*)d_in[3];
    const float* bproj = (const float*)d_in[4];
    const float* Wgat  = (const float*)d_in[5];
    const float* agat  = (const float*)d_in[6];
    const float* nemb  = (const float*)d_in[7];
    const float* lng   = (const float*)d_in[8];
    const float* lnb   = (const float*)d_in[9];
    const float* ln2g  = (const float*)d_in[10];
    const float* ln2b  = (const float*)d_in[11];
    const float* W1    = (const float*)d_in[12];
    const float* b1    = (const float*)d_in[13];
    const float* W2    = (const float*)d_in[14];
    const float* b2    = (const float*)d_in[15];
    float* out = (float*)d_out;

    float* ws = (float*)d_ws;
    float* f_sums   = ws;                       // 4096*256
    float* f_counts = f_sums   + 1048576;       // 4096
    float* f_hgnn   = f_counts + 4096;          // 4096*256
    float* f_subf   = f_hgnn   + 1048576;       // 4096*256
    float* f_bpack  = f_subf   + 1048576;       // 256*256
    float* f_wh     = f_bpack  + 65536;         // 4096*256
    float* f_fsrc   = f_wh     + 1048576;       // 2*4096
    float* f_fdst   = f_fsrc   + 8192;          // 2*4096
    float* f_subout = f_fdst   + 8192;          // 4096*256
    float* f_zn     = f_subout + 1048576;       // 4096*768
    float* f_z1     = f_zn     + 3145728;       // 4096*384

    hipMemsetAsync(f_sums, 0, (1048576 + 4096) * sizeof(float), stream);

    // 1) h_gnn_in = ht @ W_proj + b_proj
    gemm64<false, true><<<dim3(D_GNN / 64, N_NODES / 64), 256, 0, stream>>>(
        ht, Wproj, bproj, f_hgnn, N_NODES, D_GNN, D_EMB);
    // 2) scatter-mean + fallback embedding
    scatter_add<<<N_NODES, 256, 0, stream>>>(f_hgnn, nidx, f_sums, f_counts);
    combine<<<N_NODES, 256, 0, stream>>>(f_sums, f_counts, nemb, f_subf);
    // 3) Wh (both heads packed): subf @ Bpack
    packb<<<D_GNN, 256, 0, stream>>>(Wgat, f_bpack);
    gemm64<false, false><<<dim3(D_GNN / 64, N_NODES / 64), 256, 0, stream>>>(
        f_subf, f_bpack, nullptr, f_wh, N_NODES, D_GNN, D_GNN);
    // 4) attention logits halves
    fsd<<<N_NODES / 4, 256, 0, stream>>>(f_wh, agat, f_fsrc, f_fdst);
    // 5) sparse GAT attention + ELU + LN
    gat_attn<<<N_NODES, 256, 0, stream>>>(adj, f_wh, f_fsrc, f_fdst, lng, lnb, f_subout);
    // 6) gather + concat + LN(768)
    fuse_ln<<<N_NODES, 256, 0, stream>>>(ht, f_subout, nidx, ln2g, ln2b, f_zn);
    // 7) z1 = gelu(zn @ W1 + b1)
    gemm64<true, true><<<dim3(D_HID / 64, N_NODES / 64), 256, 0, stream>>>(
        f_zn, W1, b1, f_z1, N_NODES, D_HID, FUS);
    // 8) out = z1 @ W2 + b2
    outk<<<N_NODES / 4, 256, 0, stream>>>(f_z1, W2, b2, out);
}

// Round 4
// 233.798 us; speedup vs baseline: 1.3204x; 1.3204x over previous
//
#include <hip/hip_runtime.h>
#include <hip/hip_bf16.h>
#include <math.h>

#define N_NODES 4096
#define D_EMB   512
#define D_GNN   256
#define D_HEAD  128
#define FUS     768
#define D_HID   384   // FUS/2
#define MAX_NBR 512

typedef unsigned short u16;
typedef __attribute__((ext_vector_type(4))) float f4;
typedef __attribute__((ext_vector_type(4))) int   i4;
typedef __attribute__((address_space(3))) u16 lds_u16;
typedef __attribute__((address_space(1))) const u16 g_u16;

__device__ __forceinline__ u16 bfh(float x) {
    __hip_bfloat16 b = __float2bfloat16(x);
    return *(u16*)&b;
}
__device__ __forceinline__ float bff(u16 u) {
    __hip_bfloat16 b = *(__hip_bfloat16*)&u;
    return __bfloat162float(b);
}

// inline-asm MFMA: D(acc) += A*B, bf16 16x16x32
#define MFMA(acc, a, b) \
    asm volatile("v_mfma_f32_16x16x32_bf16 %0, %1, %2, %0" : "+v"(acc) : "v"(a), "v"(b))

// ---------------- block reduce (256 threads, 4 waves) ----------------
__device__ __forceinline__ float block_reduce(float v, float* red, bool is_max) {
    #pragma unroll
    for (int o = 32; o; o >>= 1)
        v = is_max ? fmaxf(v, __shfl_down(v, o)) : v + __shfl_down(v, o);
    const int wid = threadIdx.x >> 6;
    if ((threadIdx.x & 63) == 0) red[wid] = v;
    __syncthreads();
    float r;
    if (is_max) r = fmaxf(fmaxf(red[0], red[1]), fmaxf(red[2], red[3]));
    else        r = red[0] + red[1] + red[2] + red[3];
    __syncthreads();
    return r;
}

// ---------------- split fp32 -> bf16 hi/lo, row-major passthrough ----------------
__global__ __launch_bounds__(256) void split_rm(const float* __restrict__ X,
                                                u16* __restrict__ H, u16* __restrict__ L,
                                                int n4) {
    const int i = blockIdx.x * 256 + threadIdx.x;
    if (i >= n4) return;
    const float4 v = ((const float4*)X)[i];
    ushort4 h, l;
    h.x = bfh(v.x); l.x = bfh(v.x - bff(h.x));
    h.y = bfh(v.y); l.y = bfh(v.y - bff(h.y));
    h.z = bfh(v.z); l.z = bfh(v.z - bff(h.z));
    h.w = bfh(v.w); l.w = bfh(v.w - bff(h.w));
    ((ushort4*)H)[i] = h;
    ((ushort4*)L)[i] = l;
}

// ---------------- split + transpose: W (KxN fp32) -> Th/Tl (NxK bf16) ----------------
__global__ __launch_bounds__(256) void split_t(const float* __restrict__ W,
                                               u16* __restrict__ Th, u16* __restrict__ Tl,
                                               int K, int Nn) {
    __shared__ float tile[32][33];
    const int k0 = blockIdx.y * 32, n0 = blockIdx.x * 32;
    const int lx = threadIdx.x & 31, ly = threadIdx.x >> 5;
    #pragma unroll
    for (int r = ly; r < 32; r += 8)
        tile[r][lx] = W[(size_t)(k0 + r) * Nn + n0 + lx];
    __syncthreads();
    #pragma unroll
    for (int r = ly; r < 32; r += 8) {
        const float v = tile[lx][r];
        const u16 h = bfh(v);
        const size_t o = (size_t)(n0 + r) * K + k0 + lx;
        Th[o] = h;
        Tl[o] = bfh(v - bff(h));
    }
}

// ---------------- pack+transpose W_gat (H,D_GNN,d) -> Bt (D_GNN x D_GNN, bf16 hi/lo) ----------------
__global__ __launch_bounds__(256) void packbt(const float* __restrict__ Wgat,
                                              u16* __restrict__ Th, u16* __restrict__ Tl) {
    const int i = blockIdx.x;       // input dim 0..255
    const int n = threadIdx.x;      // output row = h*128+d
    const int h = n >> 7, d = n & 127;
    const float v = Wgat[(size_t)h * D_GNN * D_HEAD + (size_t)i * D_HEAD + d];
    const u16 hh = bfh(v);
    Th[(size_t)n * D_GNN + i] = hh;
    Tl[(size_t)n * D_GNN + i] = bfh(v - bff(hh));
}

// ---------------- split-bf16 MFMA GEMM: C = [gelu]([3-product A@B^T] + bias) ----------------
// Ah/Al: MxK bf16 row-major. Bh/Bl: NxK bf16 row-major (i.e. B transposed, K-major).
// 64x64 tile, BK=64, 4 waves, double-buffered global_load_lds staging.
template<bool GELU, bool HASB>
__global__ __launch_bounds__(256) void mgemm(const u16* __restrict__ Ah, const u16* __restrict__ Al,
                                             const u16* __restrict__ Bh, const u16* __restrict__ Bl,
                                             const float* __restrict__ bias, float* __restrict__ C,
                                             int M, int Nn, int K) {
    __shared__ u16 lds[2][4][4096];   // [dbuf][Ah,Al,Bh,Bl][64x64]
    const int t = threadIdx.x, w = t >> 6, l = t & 63;
    const int m0 = blockIdx.y * 64, n0 = blockIdx.x * 64;
    const int nk = K >> 6;
    const u16* pAh = Ah + (size_t)(m0 + (t >> 3)) * K + (t & 7) * 8;
    const u16* pAl = Al + (size_t)(m0 + (t >> 3)) * K + (t & 7) * 8;
    const u16* pBh = Bh + (size_t)(n0 + (t >> 3)) * K + (t & 7) * 8;
    const u16* pBl = Bl + (size_t)(n0 + (t >> 3)) * K + (t & 7) * 8;
    const int w512 = w * 512;
    const int K32 = K * 32;

#define STG(c, koff) do { \
    __builtin_amdgcn_global_load_lds((g_u16*)(pAh + (koff)),       (lds_u16*)&lds[c][0][w512],        16, 0, 0); \
    __builtin_amdgcn_global_load_lds((g_u16*)(pAh + (koff) + K32), (lds_u16*)&lds[c][0][w512 + 2048], 16, 0, 0); \
    __builtin_amdgcn_global_load_lds((g_u16*)(pAl + (koff)),       (lds_u16*)&lds[c][1][w512],        16, 0, 0); \
    __builtin_amdgcn_global_load_lds((g_u16*)(pAl + (koff) + K32), (lds_u16*)&lds[c][1][w512 + 2048], 16, 0, 0); \
    __builtin_amdgcn_global_load_lds((g_u16*)(pBh + (koff)),       (lds_u16*)&lds[c][2][w512],        16, 0, 0); \
    __builtin_amdgcn_global_load_lds((g_u16*)(pBh + (koff) + K32), (lds_u16*)&lds[c][2][w512 + 2048], 16, 0, 0); \
    __builtin_amdgcn_global_load_lds((g_u16*)(pBl + (koff)),       (lds_u16*)&lds[c][3][w512],        16, 0, 0); \
    __builtin_amdgcn_global_load_lds((g_u16*)(pBl + (koff) + K32), (lds_u16*)&lds[c][3][w512 + 2048], 16, 0, 0); \
} while (0)

    const int wm = w >> 1, wn = w & 1;
    const int lr = l & 15, lk = (l >> 4) << 3;
    // element offsets within a 64x64 bf16 tile (row*64 + col)
    int aoff[2][2], boff[2][2];
    #pragma unroll
    for (int i = 0; i < 2; ++i)
        #pragma unroll
        for (int ks = 0; ks < 2; ++ks) {
            aoff[i][ks] = (wm * 32 + i * 16 + lr) * 64 + ks * 32 + lk;
            boff[i][ks] = (wn * 32 + i * 16 + lr) * 64 + ks * 32 + lk;
        }

    f4 acc[2][2] = {};
    int cur = 0;
    STG(0, 0);
    __syncthreads();
    for (int kt = 0; kt < nk; ++kt) {
        if (kt + 1 < nk) STG(cur ^ 1, (kt + 1) * 64);
        const u16* LAh = lds[cur][0];
        const u16* LAl = lds[cur][1];
        const u16* LBh = lds[cur][2];
        const u16* LBl = lds[cur][3];
        i4 ah[2][2], al_[2][2], bh[2][2], bl_[2][2];
        #pragma unroll
        for (int i = 0; i < 2; ++i)
            #pragma unroll
            for (int ks = 0; ks < 2; ++ks) {
                ah[i][ks]  = *(const i4*)&LAh[aoff[i][ks]];
                al_[i][ks] = *(const i4*)&LAl[aoff[i][ks]];
                bh[i][ks]  = *(const i4*)&LBh[boff[i][ks]];
                bl_[i][ks] = *(const i4*)&LBl[boff[i][ks]];
            }
        #pragma unroll
        for (int i = 0; i < 2; ++i)
            #pragma unroll
            for (int j = 0; j < 2; ++j)
                #pragma unroll
                for (int ks = 0; ks < 2; ++ks) {
                    MFMA(acc[i][j], ah[i][ks],  bh[j][ks]);
                    MFMA(acc[i][j], ah[i][ks],  bl_[j][ks]);
                    MFMA(acc[i][j], al_[i][ks], bh[j][ks]);
                }
        __syncthreads();
        cur ^= 1;
    }
    asm volatile("s_nop 7\n\ts_nop 7\n\ts_nop 7");   // MFMA->VALU hazard guard
    #pragma unroll
    for (int i = 0; i < 2; ++i)
        #pragma unroll
        for (int j = 0; j < 2; ++j) {
            const int col = n0 + wn * 32 + j * 16 + lr;
            float bv = 0.f;
            if (HASB) bv = bias[col];
            #pragma unroll
            for (int r = 0; r < 4; ++r) {
                const int row = m0 + wm * 32 + i * 16 + (l >> 4) * 4 + r;
                float v = acc[i][j][r] + bv;
                if (GELU) v = 0.5f * v * (1.f + erff(v * 0.70710678118654752f));
                C[(size_t)row * Nn + col] = v;
            }
        }
#undef STG
}

// ---------------- scatter segment-sum ----------------
__global__ __launch_bounds__(256) void scatter_add(const float* __restrict__ hgnn,
                                                   const int* __restrict__ nidx,
                                                   float* __restrict__ sums,
                                                   float* __restrict__ counts) {
    const int b = blockIdx.x, t = threadIdx.x;
    const int g = nidx[b];
    atomicAdd(&sums[(size_t)g * D_GNN + t], hgnn[(size_t)b * D_GNN + t]);
    if (t == 0) atomicAdd(&counts[g], 1.0f);
}

// combine -> writes bf16 hi/lo of sub_feats (only consumer is the Wh GEMM)
__global__ __launch_bounds__(256) void combine(const float* __restrict__ sums,
                                               const float* __restrict__ counts,
                                               const float* __restrict__ nemb,
                                               u16* __restrict__ subh,
                                               u16* __restrict__ subl) {
    const int n = blockIdx.x, t = threadIdx.x;
    const float c = counts[n];
    const size_t o = (size_t)n * D_GNN + t;
    const float v = (c > 0.f) ? sums[o] / fmaxf(c, 1.f) : nemb[o];
    const u16 h = bfh(v);
    subh[o] = h;
    subl[o] = bfh(v - bff(h));
}

// ---------------- f_src/f_dst: per-row dots with a_gat halves ----------------
__global__ __launch_bounds__(256) void fsd(const float* __restrict__ Wh,
                                           const float* __restrict__ agat,
                                           float* __restrict__ fsrc,
                                           float* __restrict__ fdst) {
    const int n = blockIdx.x * 4 + (threadIdx.x >> 6);
    const int l = threadIdx.x & 63;
    const float* row = Wh + (size_t)n * D_GNN;
    const float x0 = row[l],       x1 = row[l + 64];
    const float y0 = row[128 + l], y1 = row[192 + l];
    float s0 = x0 * agat[l]       + x1 * agat[l + 64];
    float s1 = x0 * agat[128 + l] + x1 * agat[192 + l];
    float s2 = y0 * agat[256 + l] + y1 * agat[320 + l];
    float s3 = y0 * agat[384 + l] + y1 * agat[448 + l];
    #pragma unroll
    for (int o = 32; o; o >>= 1) {
        s0 += __shfl_down(s0, o); s1 += __shfl_down(s1, o);
        s2 += __shfl_down(s2, o); s3 += __shfl_down(s3, o);
    }
    if (l == 0) {
        fsrc[n] = s0;            fdst[n] = s1;
        fsrc[N_NODES + n] = s2;  fdst[N_NODES + n] = s3;
    }
}

// ---------------- GAT attention + ELU + LayerNorm (one block per node) ----------------
__global__ __launch_bounds__(256) void gat_attn(const float* __restrict__ adj,
                                                const float* __restrict__ Wh,
                                                const float* __restrict__ fsrc,
                                                const float* __restrict__ fdst,
                                                const float* __restrict__ lng,
                                                const float* __restrict__ lnb,
                                                float* __restrict__ subout) {
    const int i = blockIdx.x, t = threadIdx.x;
    const int lane = t & 63, wid = t >> 6;
    __shared__ int   s_nbr[MAX_NBR];
    __shared__ int   s_wcnt[4];
    __shared__ int   s_base;
    __shared__ float s_att[2][MAX_NBR];
    __shared__ float s_red[4];
    __shared__ float s_inv[2];
    if (t == 0) s_base = 0;
    __syncthreads();
    const float* arow = adj + (size_t)i * N_NODES;
    for (int c0 = 0; c0 < N_NODES; c0 += 256) {
        const int j = c0 + t;
        const bool hit = arow[j] > 0.f;
        const unsigned long long m = __ballot(hit);
        if (lane == 0) s_wcnt[wid] = __popcll(m);
        __syncthreads();
        int wbase = s_base;
        for (int w = 0; w < wid; ++w) wbase += s_wcnt[w];
        if (hit) {
            const int p = wbase + __popcll(m & ((1ull << lane) - 1ull));
            if (p < MAX_NBR) s_nbr[p] = j;
        }
        __syncthreads();
        if (t == 0) s_base += s_wcnt[0] + s_wcnt[1] + s_wcnt[2] + s_wcnt[3];
        __syncthreads();
    }
    const int cnt = min(s_base, MAX_NBR);
    for (int h = 0; h < 2; ++h) {
        const float fs = fsrc[h * N_NODES + i];
        const float* fd = fdst + h * N_NODES;
        float lm = -1e30f;
        for (int idx = t; idx < cnt; idx += 256) {
            float e = fs + fd[s_nbr[idx]];
            e = e > 0.f ? e : 0.2f * e;
            s_att[h][idx] = e;
            lm = fmaxf(lm, e);
        }
        const float m = block_reduce(lm, s_red, true);
        float ls = 0.f;
        for (int idx = t; idx < cnt; idx += 256) {
            const float p = expf(s_att[h][idx] - m);
            s_att[h][idx] = p;
            ls += p;
        }
        const float s = block_reduce(ls, s_red, false);
        if (t == 0) s_inv[h] = 1.f / s;
    }
    __syncthreads();
    const int h = t >> 7, d = t & 127;
    float acc = 0.f;
    for (int j = 0; j < cnt; ++j)
        acc += s_att[h][j] * Wh[(size_t)s_nbr[j] * D_GNN + h * D_HEAD + d];
    acc *= s_inv[h];
    const float v = acc > 0.f ? acc : expm1f(acc);
    const float sum  = block_reduce(v, s_red, false);
    const float sq   = block_reduce(v * v, s_red, false);
    const float mean = sum * (1.f / 256.f);
    const float var  = sq * (1.f / 256.f) - mean * mean;
    const float rstd = rsqrtf(var + 1e-5f);
    subout[(size_t)i * D_GNN + t] = (v - mean) * rstd * lng[t] + lnb[t];
}

// ---------------- gather + concat + LayerNorm(768) -> bf16 hi/lo ----------------
__global__ __launch_bounds__(256) void fuse_ln(const float* __restrict__ ht,
                                               const float* __restrict__ subout,
                                               const int* __restrict__ nidx,
                                               const float* __restrict__ g,
                                               const float* __restrict__ b,
                                               u16* __restrict__ znh,
                                               u16* __restrict__ znl) {
    const int row = blockIdx.x, t = threadIdx.x;
    __shared__ float s_red[4];
    const int gidx = nidx[row];
    const float x0 = ht[(size_t)row * D_EMB + t];
    const float x1 = ht[(size_t)row * D_EMB + 256 + t];
    const float x2 = subout[(size_t)gidx * D_GNN + t];
    const float sum = block_reduce(x0 + x1 + x2, s_red, false);
    const float sq  = block_reduce(x0 * x0 + x1 * x1 + x2 * x2, s_red, false);
    const float mean = sum * (1.f / 768.f);
    const float var  = sq * (1.f / 768.f) - mean * mean;
    const float rstd = rsqrtf(var + 1e-5f);
    const size_t base = (size_t)row * FUS;
    const float z0 = (x0 - mean) * rstd * g[t]       + b[t];
    const float z1 = (x1 - mean) * rstd * g[256 + t] + b[256 + t];
    const float z2 = (x2 - mean) * rstd * g[512 + t] + b[512 + t];
    u16 h;
    h = bfh(z0); znh[base + t]       = h; znl[base + t]       = bfh(z0 - bff(h));
    h = bfh(z1); znh[base + 256 + t] = h; znl[base + 256 + t] = bfh(z1 - bff(h));
    h = bfh(z2); znh[base + 512 + t] = h; znl[base + 512 + t] = bfh(z2 - bff(h));
}

// ---------------- final projection: out = z1 @ W2 + b2 ----------------
__global__ __launch_bounds__(256) void outk(const float* __restrict__ z1,
                                            const float* __restrict__ W2,
                                            const float* __restrict__ b2,
                                            float* __restrict__ out) {
    const int row = blockIdx.x * 4 + (threadIdx.x >> 6);
    const int l = threadIdx.x & 63;
    float acc = 0.f;
    for (int c = l; c < D_HID; c += 64)
        acc += z1[(size_t)row * D_HID + c] * W2[c];
    #pragma unroll
    for (int o = 32; o; o >>= 1) acc += __shfl_down(acc, o);
    if (l == 0) out[row] = acc + b2[0];
}

extern "C" void kernel_launch(void* const* d_in, const int* in_sizes, int n_in,
                              void* d_out, int out_size, void* d_ws, size_t ws_size,
                              hipStream_t stream) {
    const float* ht    = (const float*)d_in[0];
    const int*   nidx  = (const int*)  d_in[1];
    const float* adj   = (const float*)d_in[2];
    const float* Wproj = (const float*)d_in[3];
    const float* bproj = (const float*)d_in[4];
    const float* Wgat  = (const float*)d_in[5];
    const float* agat  = (const float*)d_in[6];
    const float* nemb  = (const float*)d_in[7];
    const float* lng   = (const float*)d_in[8];
    const float* lnb   = (const float*)d_in[9];
    const float* ln2g  = (const float*)d_in[10];
    const float* ln2b  = (const float*)d_in[11];
    const float* W1    = (const float*)d_in[12];
    const float* b1    = (const float*)d_in[13];
    const float* W2    = (const float*)d_in[14];
    const float* b2    = (const float*)d_in[15];
    float* out = (float*)d_out;

    const size_t MB = 1u << 20;
    char* base = (char*)d_ws;
    // [0,8MB): ht hi/lo (dead after mgemm1) -- reused for zn hi/lo [0,12MB)
    u16*   ht_hi  = (u16*)(base);                       // 2097152 el
    u16*   ht_lo  = ht_hi + 2097152;
    u16*   zn_hi  = (u16*)(base);                       // 3145728 el (written after ht_* dead)
    u16*   zn_lo  = zn_hi + 3145728;
    float* f_hgnn = (float*)(base + 12 * MB);           // 1048576 el (dead after scatter)
    float* f_z1   = (float*)(base + 12 * MB);           // 1572864 el (written after f_hgnn dead)
    float* f_sums = (float*)(base + 18 * MB);           // 1048576 el
    float* f_cnt  = (float*)(base + 22 * MB);           // 4096 el
    u16*   subf_h = (u16*)(base + 22 * MB + 65536);     // 1048576 el
    u16*   subf_l = subf_h + 1048576;
    u16*   bT_h   = (u16*)(base + 27 * MB);             // 65536 el
    u16*   bT_l   = bT_h + 65536;
    u16*   WpT_h  = (u16*)(base + 28 * MB);             // 131072 el
    u16*   WpT_l  = WpT_h + 131072;
    float* f_wh   = (float*)(base + 29 * MB);           // 1048576 el
    float* f_fsrc = (float*)(base + 33 * MB);           // 8192 el
    float* f_fdst = (float*)(base + 33 * MB + 32768);   // 8192 el
    float* f_subo = (float*)(base + 34 * MB);           // 1048576 el
    u16*   W1T_h  = (u16*)(base + 38 * MB);             // 294912 el
    u16*   W1T_l  = W1T_h + 294912;                     // ends ~39.2 MB

    hipMemsetAsync(f_sums, 0, (1048576 + 4096) * sizeof(float), stream);

    // 1) split inputs + weights, then h_gnn_in = ht @ W_proj + b_proj (MFMA)
    split_rm<<<2048, 256, 0, stream>>>(ht, ht_hi, ht_lo, 524288);
    split_t<<<dim3(8, 16), 256, 0, stream>>>(Wproj, WpT_h, WpT_l, D_EMB, D_GNN);
    mgemm<false, true><<<dim3(4, 64), 256, 0, stream>>>(
        ht_hi, ht_lo, WpT_h, WpT_l, bproj, f_hgnn, N_NODES, D_GNN, D_EMB);
    // 2) scatter-mean + fallback embedding (emits bf16 hi/lo)
    scatter_add<<<N_NODES, 256, 0, stream>>>(f_hgnn, nidx, f_sums, f_cnt);
    combine<<<N_NODES, 256, 0, stream>>>(f_sums, f_cnt, nemb, subf_h, subf_l);
    // 3) Wh = subf @ Wgat (both heads packed, MFMA)
    packbt<<<D_GNN, 256, 0, stream>>>(Wgat, bT_h, bT_l);
    mgemm<false, false><<<dim3(4, 64), 256, 0, stream>>>(
        subf_h, subf_l, bT_h, bT_l, nullptr, f_wh, N_NODES, D_GNN, D_GNN);
    // 4) attention logits halves
    fsd<<<N_NODES / 4, 256, 0, stream>>>(f_wh, agat, f_fsrc, f_fdst);
    // 5) sparse GAT attention + ELU + LN
    gat_attn<<<N_NODES, 256, 0, stream>>>(adj, f_wh, f_fsrc, f_fdst, lng, lnb, f_subo);
    // 6) gather + concat + LN(768) -> bf16 hi/lo
    fuse_ln<<<N_NODES, 256, 0, stream>>>(ht, f_subo, nidx, ln2g, ln2b, zn_hi, zn_lo);
    // 7) z1 = gelu(zn @ W1 + b1) (MFMA)
    split_t<<<dim3(12, 24), 256, 0, stream>>>(W1, W1T_h, W1T_l, FUS, D_HID);
    mgemm<true, true><<<dim3(6, 64), 256, 0, stream>>>(
        zn_hi, zn_lo, W1T_h, W1T_l, b1, f_z1, N_NODES, D_HID, FUS);
    // 8) out = z1 @ W2 + b2
    outk<<<N_NODES / 4, 256, 0, stream>>>(f_z1, W2, b2, out);
}

// Round 5
// 214.750 us; speedup vs baseline: 1.4375x; 1.0887x over previous
//
#include <hip/hip_runtime.h>
#include <hip/hip_bf16.h>
#include <math.h>

#define N_NODES 4096
#define D_EMB   512
#define D_GNN   256
#define D_HEAD  128
#define FUS     768
#define D_HID   384   // FUS/2
#define MAX_NBR 512

typedef unsigned short u16;
typedef __attribute__((ext_vector_type(4))) float f4;
typedef __attribute__((ext_vector_type(4))) int   i4;
typedef __attribute__((address_space(3))) u16 lds_u16;
typedef __attribute__((address_space(1))) const u16 g_u16;

__device__ __forceinline__ u16 bfh(float x) {
    __hip_bfloat16 b = __float2bfloat16(x);
    return *(u16*)&b;
}
__device__ __forceinline__ float bff(u16 u) {
    __hip_bfloat16 b = *(__hip_bfloat16*)&u;
    return __bfloat162float(b);
}

// inline-asm MFMA: D(acc) += A*B, bf16 16x16x32
#define MFMA(acc, a, b) \
    asm volatile("v_mfma_f32_16x16x32_bf16 %0, %1, %2, %0" : "+v"(acc) : "v"(a), "v"(b))

// ---------------- block reduce (256 threads, 4 waves) ----------------
__device__ __forceinline__ float block_reduce(float v, float* red, bool is_max) {
    #pragma unroll
    for (int o = 32; o; o >>= 1)
        v = is_max ? fmaxf(v, __shfl_down(v, o)) : v + __shfl_down(v, o);
    const int wid = threadIdx.x >> 6;
    if ((threadIdx.x & 63) == 0) red[wid] = v;
    __syncthreads();
    float r;
    if (is_max) r = fmaxf(fmaxf(red[0], red[1]), fmaxf(red[2], red[3]));
    else        r = red[0] + red[1] + red[2] + red[3];
    __syncthreads();
    return r;
}

// ---------------- split fp32 -> bf16 hi/lo, row-major passthrough ----------------
__global__ __launch_bounds__(256) void split_rm(const float* __restrict__ X,
                                                u16* __restrict__ H, u16* __restrict__ L,
                                                int n4) {
    const int i = blockIdx.x * 256 + threadIdx.x;
    if (i >= n4) return;
    const float4 v = ((const float4*)X)[i];
    ushort4 h, l;
    h.x = bfh(v.x); l.x = bfh(v.x - bff(h.x));
    h.y = bfh(v.y); l.y = bfh(v.y - bff(h.y));
    h.z = bfh(v.z); l.z = bfh(v.z - bff(h.z));
    h.w = bfh(v.w); l.w = bfh(v.w - bff(h.w));
    ((ushort4*)H)[i] = h;
    ((ushort4*)L)[i] = l;
}

// ---------------- split + transpose: W (KxN fp32) -> Th/Tl (NxK bf16) ----------------
__global__ __launch_bounds__(256) void split_t(const float* __restrict__ W,
                                               u16* __restrict__ Th, u16* __restrict__ Tl,
                                               int K, int Nn) {
    __shared__ float tile[32][33];
    const int k0 = blockIdx.y * 32, n0 = blockIdx.x * 32;
    const int lx = threadIdx.x & 31, ly = threadIdx.x >> 5;
    #pragma unroll
    for (int r = ly; r < 32; r += 8)
        tile[r][lx] = W[(size_t)(k0 + r) * Nn + n0 + lx];
    __syncthreads();
    #pragma unroll
    for (int r = ly; r < 32; r += 8) {
        const float v = tile[lx][r];
        const u16 h = bfh(v);
        const size_t o = (size_t)(n0 + r) * K + k0 + lx;
        Th[o] = h;
        Tl[o] = bfh(v - bff(h));
    }
}

// ---------------- pack+transpose W_gat (H,D_GNN,d) -> Bt (D_GNN x D_GNN, bf16 hi/lo) ----------------
__global__ __launch_bounds__(256) void packbt(const float* __restrict__ Wgat,
                                              u16* __restrict__ Th, u16* __restrict__ Tl) {
    const int i = blockIdx.x;       // input dim 0..255
    const int n = threadIdx.x;      // output row = h*128+d
    const int h = n >> 7, d = n & 127;
    const float v = Wgat[(size_t)h * D_GNN * D_HEAD + (size_t)i * D_HEAD + d];
    const u16 hh = bfh(v);
    Th[(size_t)n * D_GNN + i] = hh;
    Tl[(size_t)n * D_GNN + i] = bfh(v - bff(hh));
}

// ---------------- split-bf16 MFMA GEMM: C = [gelu]([3-product A@B^T] + bias) ----------------
// Ah/Al: MxK bf16 row-major. Bh/Bl: NxK bf16 row-major (i.e. B transposed, K-major).
// 64x64 tile, BK=64, 4 waves, double-buffered global_load_lds staging.
template<bool GELU, bool HASB>
__global__ __launch_bounds__(256) void mgemm(const u16* __restrict__ Ah, const u16* __restrict__ Al,
                                             const u16* __restrict__ Bh, const u16* __restrict__ Bl,
                                             const float* __restrict__ bias, float* __restrict__ C,
                                             int M, int Nn, int K) {
    __shared__ u16 lds[2][4][4096];   // [dbuf][Ah,Al,Bh,Bl][64x64]
    const int t = threadIdx.x, w = t >> 6, l = t & 63;
    const int m0 = blockIdx.y * 64, n0 = blockIdx.x * 64;
    const int nk = K >> 6;
    const u16* pAh = Ah + (size_t)(m0 + (t >> 3)) * K + (t & 7) * 8;
    const u16* pAl = Al + (size_t)(m0 + (t >> 3)) * K + (t & 7) * 8;
    const u16* pBh = Bh + (size_t)(n0 + (t >> 3)) * K + (t & 7) * 8;
    const u16* pBl = Bl + (size_t)(n0 + (t >> 3)) * K + (t & 7) * 8;
    const int w512 = w * 512;
    const int K32 = K * 32;

#define STG(c, koff) do { \
    __builtin_amdgcn_global_load_lds((g_u16*)(pAh + (koff)),       (lds_u16*)&lds[c][0][w512],        16, 0, 0); \
    __builtin_amdgcn_global_load_lds((g_u16*)(pAh + (koff) + K32), (lds_u16*)&lds[c][0][w512 + 2048], 16, 0, 0); \
    __builtin_amdgcn_global_load_lds((g_u16*)(pAl + (koff)),       (lds_u16*)&lds[c][1][w512],        16, 0, 0); \
    __builtin_amdgcn_global_load_lds((g_u16*)(pAl + (koff) + K32), (lds_u16*)&lds[c][1][w512 + 2048], 16, 0, 0); \
    __builtin_amdgcn_global_load_lds((g_u16*)(pBh + (koff)),       (lds_u16*)&lds[c][2][w512],        16, 0, 0); \
    __builtin_amdgcn_global_load_lds((g_u16*)(pBh + (koff) + K32), (lds_u16*)&lds[c][2][w512 + 2048], 16, 0, 0); \
    __builtin_amdgcn_global_load_lds((g_u16*)(pBl + (koff)),       (lds_u16*)&lds[c][3][w512],        16, 0, 0); \
    __builtin_amdgcn_global_load_lds((g_u16*)(pBl + (koff) + K32), (lds_u16*)&lds[c][3][w512 + 2048], 16, 0, 0); \
} while (0)

    const int wm = w >> 1, wn = w & 1;
    const int lr = l & 15, lk = (l >> 4) << 3;
    // element offsets within a 64x64 bf16 tile (row*64 + col)
    int aoff[2][2], boff[2][2];
    #pragma unroll
    for (int i = 0; i < 2; ++i)
        #pragma unroll
        for (int ks = 0; ks < 2; ++ks) {
            aoff[i][ks] = (wm * 32 + i * 16 + lr) * 64 + ks * 32 + lk;
            boff[i][ks] = (wn * 32 + i * 16 + lr) * 64 + ks * 32 + lk;
        }

    f4 acc[2][2] = {};
    int cur = 0;
    STG(0, 0);
    __syncthreads();
    for (int kt = 0; kt < nk; ++kt) {
        if (kt + 1 < nk) STG(cur ^ 1, (kt + 1) * 64);
        const u16* LAh = lds[cur][0];
        const u16* LAl = lds[cur][1];
        const u16* LBh = lds[cur][2];
        const u16* LBl = lds[cur][3];
        i4 ah[2][2], al_[2][2], bh[2][2], bl_[2][2];
        #pragma unroll
        for (int i = 0; i < 2; ++i)
            #pragma unroll
            for (int ks = 0; ks < 2; ++ks) {
                ah[i][ks]  = *(const i4*)&LAh[aoff[i][ks]];
                al_[i][ks] = *(const i4*)&LAl[aoff[i][ks]];
                bh[i][ks]  = *(const i4*)&LBh[boff[i][ks]];
                bl_[i][ks] = *(const i4*)&LBl[boff[i][ks]];
            }
        #pragma unroll
        for (int i = 0; i < 2; ++i)
            #pragma unroll
            for (int j = 0; j < 2; ++j)
                #pragma unroll
                for (int ks = 0; ks < 2; ++ks) {
                    MFMA(acc[i][j], ah[i][ks],  bh[j][ks]);
                    MFMA(acc[i][j], ah[i][ks],  bl_[j][ks]);
                    MFMA(acc[i][j], al_[i][ks], bh[j][ks]);
                }
        __syncthreads();
        cur ^= 1;
    }
    asm volatile("s_nop 7\n\ts_nop 7\n\ts_nop 7");   // MFMA->VALU hazard guard
    #pragma unroll
    for (int i = 0; i < 2; ++i)
        #pragma unroll
        for (int j = 0; j < 2; ++j) {
            const int col = n0 + wn * 32 + j * 16 + lr;
            float bv = 0.f;
            if (HASB) bv = bias[col];
            #pragma unroll
            for (int r = 0; r < 4; ++r) {
                const int row = m0 + wm * 32 + i * 16 + (l >> 4) * 4 + r;
                float v = acc[i][j][r] + bv;
                if (GELU) v = 0.5f * v * (1.f + erff(v * 0.70710678118654752f));
                C[(size_t)row * Nn + col] = v;
            }
        }
#undef STG
}

// ---------------- scatter segment-sum ----------------
__global__ __launch_bounds__(256) void scatter_add(const float* __restrict__ hgnn,
                                                   const int* __restrict__ nidx,
                                                   float* __restrict__ sums,
                                                   float* __restrict__ counts) {
    const int b = blockIdx.x, t = threadIdx.x;
    const int g = nidx[b];
    atomicAdd(&sums[(size_t)g * D_GNN + t], hgnn[(size_t)b * D_GNN + t]);
    if (t == 0) atomicAdd(&counts[g], 1.0f);
}

// combine -> writes bf16 hi/lo of sub_feats (only consumer is the Wh GEMM)
__global__ __launch_bounds__(256) void combine(const float* __restrict__ sums,
                                               const float* __restrict__ counts,
                                               const float* __restrict__ nemb,
                                               u16* __restrict__ subh,
                                               u16* __restrict__ subl) {
    const int n = blockIdx.x, t = threadIdx.x;
    const float c = counts[n];
    const size_t o = (size_t)n * D_GNN + t;
    const float v = (c > 0.f) ? sums[o] / fmaxf(c, 1.f) : nemb[o];
    const u16 h = bfh(v);
    subh[o] = h;
    subl[o] = bfh(v - bff(h));
}

// ---------------- f_src/f_dst: per-row dots with a_gat halves ----------------
__global__ __launch_bounds__(256) void fsd(const float* __restrict__ Wh,
                                           const float* __restrict__ agat,
                                           float* __restrict__ fsrc,
                                           float* __restrict__ fdst) {
    const int n = blockIdx.x * 4 + (threadIdx.x >> 6);
    const int l = threadIdx.x & 63;
    const float* row = Wh + (size_t)n * D_GNN;
    const float x0 = row[l],       x1 = row[l + 64];
    const float y0 = row[128 + l], y1 = row[192 + l];
    float s0 = x0 * agat[l]       + x1 * agat[l + 64];
    float s1 = x0 * agat[128 + l] + x1 * agat[192 + l];
    float s2 = y0 * agat[256 + l] + y1 * agat[320 + l];
    float s3 = y0 * agat[384 + l] + y1 * agat[448 + l];
    #pragma unroll
    for (int o = 32; o; o >>= 1) {
        s0 += __shfl_down(s0, o); s1 += __shfl_down(s1, o);
        s2 += __shfl_down(s2, o); s3 += __shfl_down(s3, o);
    }
    if (l == 0) {
        fsrc[n] = s0;            fdst[n] = s1;
        fsrc[N_NODES + n] = s2;  fdst[N_NODES + n] = s3;
    }
}

// ---------------- GAT attention + ELU + LayerNorm (one block per node) ----------------
// Single-pass register compaction: thread t owns columns [16t,16t+16) loaded as
// 4x float4 (MLP=4); hit mask in registers; one shfl_up prefix + one LDS step.
// Neighbor list stays in ascending column order -> summation order identical to
// the previous (verified) version.
__global__ __launch_bounds__(256) void gat_attn(const float* __restrict__ adj,
                                                const float* __restrict__ Wh,
                                                const float* __restrict__ fsrc,
                                                const float* __restrict__ fdst,
                                                const float* __restrict__ lng,
                                                const float* __restrict__ lnb,
                                                float* __restrict__ subout) {
    const int i = blockIdx.x, t = threadIdx.x;
    const int lane = t & 63, wid = t >> 6;
    __shared__ int   s_nbr[MAX_NBR];
    __shared__ int   s_wsum[4];
    __shared__ float s_att[2][MAX_NBR];
    __shared__ float s_red[4];
    __shared__ float s_inv[2];

    // ---- load 16 columns as 4x float4, build hit mask ----
    const float4* arow4 = (const float4*)(adj + (size_t)i * N_NODES) + t * 4;
    const float4 c0 = arow4[0], c1 = arow4[1], c2 = arow4[2], c3 = arow4[3];
    float v[16];
    *(float4*)&v[0]  = c0; *(float4*)&v[4]  = c1;
    *(float4*)&v[8]  = c2; *(float4*)&v[12] = c3;
    int mask = 0;
    #pragma unroll
    for (int k = 0; k < 16; ++k) mask |= (v[k] > 0.f) ? (1 << k) : 0;
    const int cnt_t = __popc(mask);

    // ---- wave-level inclusive prefix of per-thread counts ----
    int pre = cnt_t;
    #pragma unroll
    for (int o = 1; o < 64; o <<= 1) {
        const int u = __shfl_up(pre, o);
        if (lane >= o) pre += u;
    }
    if (lane == 63) s_wsum[wid] = pre;
    __syncthreads();
    int base = 0;
    for (int w = 0; w < wid; ++w) base += s_wsum[w];
    const int total = s_wsum[0] + s_wsum[1] + s_wsum[2] + s_wsum[3];
    int off = base + pre - cnt_t;   // exclusive prefix
    #pragma unroll
    for (int k = 0; k < 16; ++k)
        if ((mask >> k) & 1) {
            if (off < MAX_NBR) s_nbr[off] = t * 16 + k;
            ++off;
        }
    __syncthreads();
    const int cnt = min(total, MAX_NBR);

    // ---- per-head softmax over neighbors ----
    for (int h = 0; h < 2; ++h) {
        const float fs = fsrc[h * N_NODES + i];
        const float* fd = fdst + h * N_NODES;
        float lm = -1e30f;
        for (int idx = t; idx < cnt; idx += 256) {
            float e = fs + fd[s_nbr[idx]];
            e = e > 0.f ? e : 0.2f * e;     // leaky relu
            s_att[h][idx] = e;
            lm = fmaxf(lm, e);
        }
        const float m = block_reduce(lm, s_red, true);
        float ls = 0.f;
        for (int idx = t; idx < cnt; idx += 256) {
            const float p = expf(s_att[h][idx] - m);
            s_att[h][idx] = p;
            ls += p;
        }
        const float s = block_reduce(ls, s_red, false);
        if (t == 0) s_inv[h] = 1.f / s;
    }
    __syncthreads();

    // ---- aggregation + ELU + LayerNorm ----
    const int h = t >> 7, d = t & 127;
    float acc = 0.f;
    for (int j = 0; j < cnt; ++j)
        acc += s_att[h][j] * Wh[(size_t)s_nbr[j] * D_GNN + h * D_HEAD + d];
    acc *= s_inv[h];
    const float vv = acc > 0.f ? acc : expm1f(acc);   // ELU
    const float sum  = block_reduce(vv, s_red, false);
    const float sq   = block_reduce(vv * vv, s_red, false);
    const float mean = sum * (1.f / 256.f);
    const float var  = sq * (1.f / 256.f) - mean * mean;
    const float rstd = rsqrtf(var + 1e-5f);
    subout[(size_t)i * D_GNN + t] = (vv - mean) * rstd * lng[t] + lnb[t];
}

// ---------------- gather + concat + LayerNorm(768) -> bf16 hi/lo ----------------
__global__ __launch_bounds__(256) void fuse_ln(const float* __restrict__ ht,
                                               const float* __restrict__ subout,
                                               const int* __restrict__ nidx,
                                               const float* __restrict__ g,
                                               const float* __restrict__ b,
                                               u16* __restrict__ znh,
                                               u16* __restrict__ znl) {
    const int row = blockIdx.x, t = threadIdx.x;
    __shared__ float s_red[4];
    const int gidx = nidx[row];
    const float x0 = ht[(size_t)row * D_EMB + t];
    const float x1 = ht[(size_t)row * D_EMB + 256 + t];
    const float x2 = subout[(size_t)gidx * D_GNN + t];
    const float sum = block_reduce(x0 + x1 + x2, s_red, false);
    const float sq  = block_reduce(x0 * x0 + x1 * x1 + x2 * x2, s_red, false);
    const float mean = sum * (1.f / 768.f);
    const float var  = sq * (1.f / 768.f) - mean * mean;
    const float rstd = rsqrtf(var + 1e-5f);
    const size_t base = (size_t)row * FUS;
    const float z0 = (x0 - mean) * rstd * g[t]       + b[t];
    const float z1 = (x1 - mean) * rstd * g[256 + t] + b[256 + t];
    const float z2 = (x2 - mean) * rstd * g[512 + t] + b[512 + t];
    u16 h;
    h = bfh(z0); znh[base + t]       = h; znl[base + t]       = bfh(z0 - bff(h));
    h = bfh(z1); znh[base + 256 + t] = h; znl[base + 256 + t] = bfh(z1 - bff(h));
    h = bfh(z2); znh[base + 512 + t] = h; znl[base + 512 + t] = bfh(z2 - bff(h));
}

// ---------------- final projection: out = z1 @ W2 + b2 ----------------
__global__ __launch_bounds__(256) void outk(const float* __restrict__ z1,
                                            const float* __restrict__ W2,
                                            const float* __restrict__ b2,
                                            float* __restrict__ out) {
    const int row = blockIdx.x * 4 + (threadIdx.x >> 6);
    const int l = threadIdx.x & 63;
    float acc = 0.f;
    for (int c = l; c < D_HID; c += 64)
        acc += z1[(size_t)row * D_HID + c] * W2[c];
    #pragma unroll
    for (int o = 32; o; o >>= 1) acc += __shfl_down(acc, o);
    if (l == 0) out[row] = acc + b2[0];
}

extern "C" void kernel_launch(void* const* d_in, const int* in_sizes, int n_in,
                              void* d_out, int out_size, void* d_ws, size_t ws_size,
                              hipStream_t stream) {
    const float* ht    = (const float*)d_in[0];
    const int*   nidx  = (const int*)  d_in[1];
    const float* adj   = (const float*)d_in[2];
    const float* Wproj = (const float*)d_in[3];
    const float* bproj = (const float*)d_in[4];
    const float* Wgat  = (const float*)d_in[5];
    const float* agat  = (const float*)d_in[6];
    const float* nemb  = (const float*)d_in[7];
    const float* lng   = (const float*)d_in[8];
    const float* lnb   = (const float*)d_in[9];
    const float* ln2g  = (const float*)d_in[10];
    const float* ln2b  = (const float*)d_in[11];
    const float* W1    = (const float*)d_in[12];
    const float* b1    = (const float*)d_in[13];
    const float* W2    = (const float*)d_in[14];
    const float* b2    = (const float*)d_in[15];
    float* out = (float*)d_out;

    const size_t MB = 1u << 20;
    char* base = (char*)d_ws;
    // [0,8MB): ht hi/lo (dead after mgemm1) -- reused for zn hi/lo [0,12MB)
    u16*   ht_hi  = (u16*)(base);                       // 2097152 el
    u16*   ht_lo  = ht_hi + 2097152;
    u16*   zn_hi  = (u16*)(base);                       // 3145728 el (written after ht_* dead)
    u16*   zn_lo  = zn_hi + 3145728;
    float* f_hgnn = (float*)(base + 12 * MB);           // 1048576 el (dead after scatter)
    float* f_z1   = (float*)(base + 12 * MB);           // 1572864 el (written after f_hgnn dead)
    float* f_sums = (float*)(base + 18 * MB);           // 1048576 el
    float* f_cnt  = (float*)(base + 22 * MB);           // 4096 el
    u16*   subf_h = (u16*)(base + 22 * MB + 65536);     // 1048576 el
    u16*   subf_l = subf_h + 1048576;
    u16*   bT_h   = (u16*)(base + 27 * MB);             // 65536 el
    u16*   bT_l   = bT_h + 65536;
    u16*   WpT_h  = (u16*)(base + 28 * MB);             // 131072 el
    u16*   WpT_l  = WpT_h + 131072;
    float* f_wh   = (float*)(base + 29 * MB);           // 1048576 el
    float* f_fsrc = (float*)(base + 33 * MB);           // 8192 el
    float* f_fdst = (float*)(base + 33 * MB + 32768);   // 8192 el
    float* f_subo = (float*)(base + 34 * MB);           // 1048576 el
    u16*   W1T_h  = (u16*)(base + 38 * MB);             // 294912 el
    u16*   W1T_l  = W1T_h + 294912;                     // ends ~39.2 MB

    hipMemsetAsync(f_sums, 0, (1048576 + 4096) * sizeof(float), stream);

    // 1) split inputs + weights, then h_gnn_in = ht @ W_proj + b_proj (MFMA)
    split_rm<<<2048, 256, 0, stream>>>(ht, ht_hi, ht_lo, 524288);
    split_t<<<dim3(8, 16), 256, 0, stream>>>(Wproj, WpT_h, WpT_l, D_EMB, D_GNN);
    mgemm<false, true><<<dim3(4, 64), 256, 0, stream>>>(
        ht_hi, ht_lo, WpT_h, WpT_l, bproj, f_hgnn, N_NODES, D_GNN, D_EMB);
    // 2) scatter-mean + fallback embedding (emits bf16 hi/lo)
    scatter_add<<<N_NODES, 256, 0, stream>>>(f_hgnn, nidx, f_sums, f_cnt);
    combine<<<N_NODES, 256, 0, stream>>>(f_sums, f_cnt, nemb, subf_h, subf_l);
    // 3) Wh = subf @ Wgat (both heads packed, MFMA)
    packbt<<<D_GNN, 256, 0, stream>>>(Wgat, bT_h, bT_l);
    mgemm<false, false><<<dim3(4, 64), 256, 0, stream>>>(
        subf_h, subf_l, bT_h, bT_l, nullptr, f_wh, N_NODES, D_GNN, D_GNN);
    // 4) attention logits halves
    fsd<<<N_NODES / 4, 256, 0, stream>>>(f_wh, agat, f_fsrc, f_fdst);
    // 5) sparse GAT attention + ELU + LN
    gat_attn<<<N_NODES, 256, 0, stream>>>(adj, f_wh, f_fsrc, f_fdst, lng, lnb, f_subo);
    // 6) gather + concat + LN(768) -> bf16 hi/lo
    fuse_ln<<<N_NODES, 256, 0, stream>>>(ht, f_subo, nidx, ln2g, ln2b, zn_hi, zn_lo);
    // 7) z1 = gelu(zn @ W1 + b1) (MFMA)
    split_t<<<dim3(12, 24), 256, 0, stream>>>(W1, W1T_h, W1T_l, FUS, D_HID);
    mgemm<true, true><<<dim3(6, 64), 256, 0, stream>>>(
        zn_hi, zn_lo, W1T_h, W1T_l, b1, f_z1, N_NODES, D_HID, FUS);
    // 8) out = z1 @ W2 + b2
    outk<<<N_NODES / 4, 256, 0, stream>>>(f_z1, W2, b2, out);
}